// Round 3
// baseline (548.083 us; speedup 1.0000x reference)
//
#include <hip/hip_runtime.h>

#define VOCAB   50000
#define LDIM    8921
#define DDIM    300
#define DPAD    320
#define KSZ     10
#define BATCH   8
#define TSEQ    2048
#define PADL    9
#define TPRIME  2057
#define TPADDED 2066
#define LPAD    8928

// ---- attn tiling
#define TSTG    32                 // t rows per LDS tile
#define NTT     65                 // ceil(TPRIME/TSTG)
#define TALLOC  (NTT * TSTG)       // 2080 h rows per batch (tail rows zeroed by conv)
#define LBLK    70                 // ceil(LDIM/128) l-blocks

typedef short s8v __attribute__((ext_vector_type(8)));   // 8 x bf16 bits
typedef float f4v __attribute__((ext_vector_type(4)));

typedef const __attribute__((address_space(1))) unsigned int* gas_ptr;
typedef __attribute__((address_space(3))) unsigned int* las_ptr;

__device__ inline unsigned short f2bf(float f) {
  union { float f; unsigned u; } v; v.f = f;
  unsigned r = v.u + 0x7FFF + ((v.u >> 16) & 1);
  return (unsigned short)(r >> 16);
}

// ---- K1: embedding gather -> xp_bf16[b][tau][DPAD], zero-padded rows/cols
// Packed 4B stores (2 bf16 cols per lane); loads value-guarded (no OOB reads).
__global__ __launch_bounds__(256) void gather_kernel(
    const int* __restrict__ ids, const float* __restrict__ embed_w,
    unsigned short* __restrict__ xp) {
  int wid = blockIdx.x * 4 + (threadIdx.x >> 6);
  int lane = threadIdx.x & 63;
  int b = wid / TPADDED, tau = wid % TPADDED;
  bool inr = (tau >= PADL) && (tau < PADL + TSEQ);
  int row = inr ? ids[b * TSEQ + (tau - PADL)] : 0;
  const float* src = embed_w + (size_t)row * DDIM;
  unsigned short* dst = xp + ((size_t)b * TPADDED + tau) * DPAD;
#pragma unroll
  for (int j = 0; j < 3; ++j) {
    int c2 = (j * 64 + lane) * 2;
    if (c2 < DPAD) {
      float v0 = (inr && c2 < DDIM) ? src[c2] : 0.0f;
      float v1 = (inr && c2 + 1 < DDIM) ? src[c2 + 1] : 0.0f;
      unsigned pk = (unsigned)f2bf(v0) | ((unsigned)f2bf(v1) << 16);
      *(unsigned*)&dst[c2] = pk;
    }
  }
}

// ---- K2: conv weight transform -> wT[k][o][i] bf16, o/i padded to 320 with 0
__global__ __launch_bounds__(256) void wt_kernel(
    const float* __restrict__ w, unsigned short* __restrict__ wT) {
  int k = blockIdx.x / DPAD, o = blockIdx.x % DPAD;
  for (int i = threadIdx.x; i < DPAD; i += 256) {
    float v = (o < DDIM && i < DDIM) ? w[((size_t)o * DDIM + i) * KSZ + k] : 0.0f;
    wT[((size_t)k * DPAD + o) * DPAD + i] = f2bf(v);
  }
}

// ---- K3: U transform -> Ub[l][d] bf16, l padded to 8928, d to 320 with 0
__global__ __launch_bounds__(256) void ut_kernel(
    const float* __restrict__ U, unsigned short* __restrict__ Ub) {
  int l = blockIdx.x;
  for (int d = threadIdx.x; d < DPAD; d += 256) {
    float v = (l < LDIM && d < DDIM) ? U[(size_t)l * DDIM + d] : 0.0f;
    Ub[(size_t)l * DPAD + d] = f2bf(v);
  }
}

// ---- K4: conv via MFMA — occupancy-restructured.
// Was: 264 blocks x 4 waves = 1 wave/SIMD (MfmaUtil 11%, pure latency exposure).
// Now: 512 threads / 8 waves (o-quadrant x t-half), CTN=32 -> grid 520 =
// 2 blocks/CU x 8 waves = 4 waves/SIMD. acc[5][1], live set ~100 VGPR,
// launch_bounds(512,4) caps at 128 (no spill expected). LDS 26.9KB.
// h rows [TPRIME,TALLOC) written as zeros so attn consumes unmasked.
#define CTN 32
#define CROWS 41          // CTN + KSZ - 1
#define CSTRIDE 328       // 656B/row -> benign 2-way conflicts
__global__ __launch_bounds__(512, 4) void conv_mfma_kernel(
    const unsigned short* __restrict__ xp, const unsigned short* __restrict__ wT,
    const float* __restrict__ bias, unsigned short* __restrict__ h) {
  __shared__ unsigned short xls[CROWS * CSTRIDE];
  int b = blockIdx.x & 7, tb = blockIdx.x >> 3;
  int t0 = tb * CTN;
  int tid = threadIdx.x;
  {
    const unsigned short* src = xp + (size_t)b * TPADDED * DPAD;
    for (int idx = tid; idx < CROWS * (DPAD / 8); idx += 512) {
      int r = idx / 40, c8 = idx % 40;
      int tp = t0 + r;
      int4 v = make_int4(0, 0, 0, 0);
      if (tp < TPADDED) v = *(const int4*)&src[(size_t)tp * DPAD + c8 * 8];
      *(int4*)&xls[r * CSTRIDE + c8 * 8] = v;
    }
  }
  __syncthreads();
  int ww = tid >> 6, lane = tid & 63;
  int wo = ww & 3;            // o-quadrant: 80 outputs
  int wt = ww >> 2;           // t-half: 16 t
  int l15 = lane & 15, quad = lane >> 4;
  f4v acc[5];
#pragma unroll
  for (int mf = 0; mf < 5; ++mf) {
#pragma unroll
    for (int r = 0; r < 4; ++r) {
      int o = wo * 80 + mf * 16 + quad * 4 + r;
      acc[mf][r] = (o < DDIM) ? bias[o] : 0.0f;
    }
  }
  s8v Acur[5], Anext[5];
#pragma unroll
  for (int mf = 0; mf < 5; ++mf)
    Acur[mf] = *(const s8v*)&wT[(size_t)(wo * 80 + mf * 16 + l15) * DPAD + quad * 8];
  for (int iter = 0; iter < 100; ++iter) {
    int kc = iter / 10, it = iter % 10;
    if (iter < 99) {
      int kn = (iter + 1) / 10, itn = (iter + 1) % 10;
#pragma unroll
      for (int mf = 0; mf < 5; ++mf)
        Anext[mf] = *(const s8v*)&wT[((size_t)kn * DPAD + wo * 80 + mf * 16 + l15) * DPAD + itn * 32 + quad * 8];
    }
    int rrow = wt * 16 + l15 + kc;
    s8v Bv = *(const s8v*)&xls[rrow * CSTRIDE + it * 32 + quad * 8];
#pragma unroll
    for (int mf = 0; mf < 5; ++mf)
      acc[mf] = __builtin_amdgcn_mfma_f32_16x16x32_bf16(Acur[mf], Bv, acc[mf], 0, 0, 0);
#pragma unroll
    for (int mf = 0; mf < 5; ++mf) Acur[mf] = Anext[mf];
  }
  int t = t0 + wt * 16 + l15;
  if (t < TALLOC) {
    bool live = t < TPRIME;
#pragma unroll
    for (int mf = 0; mf < 5; ++mf) {
      int obase = wo * 80 + mf * 16 + quad * 4;
      unsigned short pk[4];
#pragma unroll
      for (int r = 0; r < 4; ++r)
        pk[r] = live ? f2bf(fmaxf(acc[mf][r], 0.0f)) : (unsigned short)0;
      *(uint2*)&h[((size_t)b * TALLOC + t) * DPAD + obase] = *(uint2*)pk;
    }
  }
}

// ---- K5: scores (U . h) via MFMA + fused softmax-weighted mean.
// Waves split L (32 l each); all 20 U A-frags live in 80 VGPRs, loaded once.
// h streamed via global_load_lds DMA (no staging VGPRs / ds_writes):
//   linear LDS dest + involution-swizzled SOURCE chunks (c ^= r&7 within
//   128B groups) + same XOR on read side (rule #21) -> conflict-free reads
//   with pad-free 640B rows (LDS 40960B -> 3 blocks/CU).
// Depth-1 prefetch; raw s_barrier + vmcnt(0) drained a full tile after issue.
__global__ __launch_bounds__(256, 3) void attn_mfma_kernel(
    const unsigned short* __restrict__ h, const unsigned short* __restrict__ Ub,
    const float* __restrict__ fcb, float* __restrict__ out) {
  __shared__ unsigned short hls[2 * TSTG * DPAD];   // 2 x 10240 elems = 40960B
  int b = blockIdx.x & 7, lb = blockIdx.x >> 3;
  int tid = threadIdx.x;
  int w = tid >> 6, lane = tid & 63;
  int l15 = lane & 15, quad = lane >> 4;
  const unsigned short* hb = h + (size_t)b * TALLOC * DPAD;

  // A fragments (U) in registers for the whole kernel: wave covers 32 l-rows
  s8v A[2][10];
  {
    int lr0 = lb * 128 + w * 32 + l15;
#pragma unroll
    for (int mf = 0; mf < 2; ++mf) {
      int lr = lr0 + mf * 16;
      if (lr >= LPAD) lr = LPAD - 1;          // clamped rows masked at store
      const unsigned short* up = Ub + (size_t)lr * DPAD + quad * 8;
#pragma unroll
      for (int kc = 0; kc < 10; ++kc)
        A[mf][kc] = *(const s8v*)&up[kc * 32];
    }
  }

  // DMA staging map: wave w fills LDS elems [w*2560, w*2560+2560) in 5 x 1KB.
  // lane's LDS chunk g = w*320 + j*64 + lane -> row r = g/40, chunk c = g%40;
  // global source chunk = c ^ (r&7)  (involution, stays in 128B group)
  int srcoff[5];
#pragma unroll
  for (int j = 0; j < 5; ++j) {
    int g = w * 320 + j * 64 + lane;
    int r = g / 40, c = g % 40;
    srcoff[j] = r * DPAD + ((c ^ (r & 7)) * 8);
  }

  // prologue: DMA tile 0 -> buf0
#pragma unroll
  for (int j = 0; j < 5; ++j)
    __builtin_amdgcn_global_load_lds((gas_ptr)(const void*)(hb + srcoff[j]),
                                     (las_ptr)(void*)&hls[w * 2560 + j * 512],
                                     16, 0, 0);
  asm volatile("s_waitcnt vmcnt(0)" ::: "memory");
  __builtin_amdgcn_s_barrier();

  float se[2][4], sw[2][4];
#pragma unroll
  for (int mf = 0; mf < 2; ++mf)
#pragma unroll
    for (int r = 0; r < 4; ++r) { se[mf][r] = 0.0f; sw[mf][r] = 0.0f; }

  int xr8 = (l15 & 7) * 8;            // read-side XOR (elem units)
  int rowb0 = l15 * DPAD;             // nf=0 row base
  int rowb1 = (16 + l15) * DPAD;      // nf=1 row base
  int bufsel = 0;
  for (int t = 0; t < NTT; ++t) {
    // issue DMA for tile t+1 into the other buffer (latency hidden by compute)
    if (t + 1 < NTT) {
      const unsigned short* src = hb + (size_t)(t + 1) * TSTG * DPAD;
      int dstb = (bufsel ^ 1) * 10240 + w * 2560;
#pragma unroll
      for (int j = 0; j < 5; ++j)
        __builtin_amdgcn_global_load_lds((gas_ptr)(const void*)(src + srcoff[j]),
                                         (las_ptr)(void*)&hls[dstb + j * 512],
                                         16, 0, 0);
    }
    const unsigned short* bufc = &hls[bufsel * 10240];
    f4v acc[2][2];
#pragma unroll
    for (int mf = 0; mf < 2; ++mf)
#pragma unroll
      for (int nf = 0; nf < 2; ++nf) {
        acc[mf][nf][0] = 0.0f; acc[mf][nf][1] = 0.0f;
        acc[mf][nf][2] = 0.0f; acc[mf][nf][3] = 0.0f;
      }
#pragma unroll
    for (int kc = 0; kc < 10; ++kc) {
      int ko = (kc * 32 + quad * 8) ^ xr8;
      s8v Bv0 = *(const s8v*)&bufc[rowb0 + ko];
      s8v Bv1 = *(const s8v*)&bufc[rowb1 + ko];
      acc[0][0] = __builtin_amdgcn_mfma_f32_16x16x32_bf16(A[0][kc], Bv0, acc[0][0], 0, 0, 0);
      acc[0][1] = __builtin_amdgcn_mfma_f32_16x16x32_bf16(A[0][kc], Bv1, acc[0][1], 0, 0, 0);
      acc[1][0] = __builtin_amdgcn_mfma_f32_16x16x32_bf16(A[1][kc], Bv0, acc[1][0], 0, 0, 0);
      acc[1][1] = __builtin_amdgcn_mfma_f32_16x16x32_bf16(A[1][kc], Bv1, acc[1][1], 0, 0, 0);
    }
    // fused softmax-weighted accumulation (tail rows of h are zeros, t>=TPRIME masked)
    int tb0 = t * TSTG;
#pragma unroll
    for (int nf = 0; nf < 2; ++nf) {
      bool valid = (tb0 + nf * 16 + l15) < TPRIME;
#pragma unroll
      for (int mf = 0; mf < 2; ++mf)
#pragma unroll
        for (int r = 0; r < 4; ++r) {
          float s = acc[mf][nf][r];
          float e = valid ? __expf(s) : 0.0f;
          se[mf][r] += e;
          sw[mf][r] = fmaf(e, valid ? s : 0.0f, sw[mf][r]);
        }
    }
    // drain this iter's DMA (issued ~a full tile of compute ago), sync, swap
    asm volatile("s_waitcnt vmcnt(0)" ::: "memory");
    __builtin_amdgcn_s_barrier();
    bufsel ^= 1;
  }

  // reduce over the 16 t-columns (l15 lanes) — no cross-wave reduction needed
#pragma unroll
  for (int mf = 0; mf < 2; ++mf)
#pragma unroll
    for (int r = 0; r < 4; ++r) {
      float a = se[mf][r], c = sw[mf][r];
#pragma unroll
      for (int off = 1; off < 16; off <<= 1) {
        a += __shfl_xor(a, off, 64);
        c += __shfl_xor(c, off, 64);
      }
      if (l15 == 0) {
        int l = lb * 128 + w * 32 + mf * 16 + quad * 4 + r;
        if (l < LDIM) out[(size_t)b * LDIM + l] = c / a + fcb[l];
      }
    }
}

extern "C" void kernel_launch(void* const* d_in, const int* in_sizes, int n_in,
                              void* d_out, int out_size, void* d_ws, size_t ws_size,
                              hipStream_t stream) {
  const int*   ids     = (const int*)d_in[0];
  const float* embed_w = (const float*)d_in[1];
  const float* conv_w  = (const float*)d_in[2];
  const float* conv_b  = (const float*)d_in[3];
  const float* U       = (const float*)d_in[4];
  const float* fc_bias = (const float*)d_in[5];
  float* out = (float*)d_out;

  unsigned char* p = (unsigned char*)d_ws;
  unsigned short* xp = (unsigned short*)p;                 p += (size_t)BATCH * TPADDED * DPAD * 2;
  unsigned short* hb = (unsigned short*)p;                 p += (size_t)BATCH * TALLOC * DPAD * 2;
  unsigned short* wT = (unsigned short*)p;                 p += (size_t)KSZ * DPAD * DPAD * 2;
  unsigned short* Ub = (unsigned short*)p;

  hipLaunchKernelGGL(gather_kernel, dim3(BATCH * TPADDED / 4), dim3(256), 0, stream,
                     ids, embed_w, xp);
  hipLaunchKernelGGL(wt_kernel, dim3(KSZ * DPAD), dim3(256), 0, stream, conv_w, wT);
  hipLaunchKernelGGL(ut_kernel, dim3(LPAD), dim3(256), 0, stream, U, Ub);
  hipLaunchKernelGGL(conv_mfma_kernel, dim3(BATCH * NTT), dim3(512), 0, stream,
                     xp, wT, conv_b, hb);
  hipLaunchKernelGGL(attn_mfma_kernel, dim3(BATCH * LBLK), dim3(256), 0, stream,
                     hb, Ub, fc_bias, out);
}

// Round 4
// 390.109 us; speedup vs baseline: 1.4049x; 1.4049x over previous
//
#include <hip/hip_runtime.h>

#define VOCAB   50000
#define LDIM    8921
#define DDIM    300
#define DPAD    320
#define KSZ     10
#define BATCH   8
#define TSEQ    2048
#define PADL    9
#define TPRIME  2057
#define TPADDED 2066
#define LPAD    8928

// ---- attn tiling
#define TSTG    32                 // t rows per LDS tile
#define NTT     65                 // ceil(TPRIME/TSTG)
#define TALLOC  (NTT * TSTG)       // 2080 h rows per batch (tail rows zeroed by conv)
#define LBLK    70                 // ceil(LDIM/128) l-blocks

typedef short s8v __attribute__((ext_vector_type(8)));   // 8 x bf16 bits
typedef float f4v __attribute__((ext_vector_type(4)));

typedef const __attribute__((address_space(1))) unsigned int* gas_ptr;
typedef __attribute__((address_space(3))) unsigned int* las_ptr;

__device__ inline unsigned short f2bf(float f) {
  union { float f; unsigned u; } v; v.f = f;
  unsigned r = v.u + 0x7FFF + ((v.u >> 16) & 1);
  return (unsigned short)(r >> 16);
}

// ---- K1: embedding gather -> xp_bf16[b][tau][DPAD], zero-padded rows/cols
// Packed 4B stores (2 bf16 cols per lane); loads value-guarded (no OOB reads).
__global__ __launch_bounds__(256) void gather_kernel(
    const int* __restrict__ ids, const float* __restrict__ embed_w,
    unsigned short* __restrict__ xp) {
  int wid = blockIdx.x * 4 + (threadIdx.x >> 6);
  int lane = threadIdx.x & 63;
  int b = wid / TPADDED, tau = wid % TPADDED;
  bool inr = (tau >= PADL) && (tau < PADL + TSEQ);
  int row = inr ? ids[b * TSEQ + (tau - PADL)] : 0;
  const float* src = embed_w + (size_t)row * DDIM;
  unsigned short* dst = xp + ((size_t)b * TPADDED + tau) * DPAD;
#pragma unroll
  for (int j = 0; j < 3; ++j) {
    int c2 = (j * 64 + lane) * 2;
    if (c2 < DPAD) {
      float v0 = (inr && c2 < DDIM) ? src[c2] : 0.0f;
      float v1 = (inr && c2 + 1 < DDIM) ? src[c2 + 1] : 0.0f;
      unsigned pk = (unsigned)f2bf(v0) | ((unsigned)f2bf(v1) << 16);
      *(unsigned*)&dst[c2] = pk;
    }
  }
}

// ---- K2: conv weight transform -> wT[k][o][i] bf16, o/i padded to 320 with 0
__global__ __launch_bounds__(256) void wt_kernel(
    const float* __restrict__ w, unsigned short* __restrict__ wT) {
  int k = blockIdx.x / DPAD, o = blockIdx.x % DPAD;
  for (int i = threadIdx.x; i < DPAD; i += 256) {
    float v = (o < DDIM && i < DDIM) ? w[((size_t)o * DDIM + i) * KSZ + k] : 0.0f;
    wT[((size_t)k * DPAD + o) * DPAD + i] = f2bf(v);
  }
}

// ---- K3: U transform -> Ub[l][d] bf16, l padded to 8928, d to 320 with 0
__global__ __launch_bounds__(256) void ut_kernel(
    const float* __restrict__ U, unsigned short* __restrict__ Ub) {
  int l = blockIdx.x;
  for (int d = threadIdx.x; d < DPAD; d += 256) {
    float v = (l < LDIM && d < DDIM) ? U[(size_t)l * DDIM + d] : 0.0f;
    Ub[(size_t)l * DPAD + d] = f2bf(v);
  }
}

// ---- K4: conv via MFMA — round-2 inner loop (proven 123us), occupancy via
// o-half block split: grid 8 x 33 x 2 = 528 blocks (~2 blocks/CU = 2 waves/SIMD,
// 2x the latency cover of round 2's 1 wave/SIMD). Waves: 2-o x 2-t within block.
// acc[5][2]; generous launch_bounds(256,2) — round 3 showed tight caps force
// scratch demotion (VGPR_Count 36, 3x regression). #pragma unroll 10 folds the
// /10 %10 address math. h rows [TPRIME,TALLOC) written as zeros.
#define CTN 64
#define CROWS 73          // CTN + KSZ - 1
#define CSTRIDE 328       // 656B/row -> benign 2-way conflicts
__global__ __launch_bounds__(256, 2) void conv_mfma_kernel(
    const unsigned short* __restrict__ xp, const unsigned short* __restrict__ wT,
    const float* __restrict__ bias, unsigned short* __restrict__ h) {
  __shared__ unsigned short xls[CROWS * CSTRIDE];
  int b = blockIdx.x & 7, r = blockIdx.x >> 3;
  int tb = r >> 1, oh = r & 1;
  int t0 = tb * CTN;
  int tid = threadIdx.x;
  {
    const unsigned short* src = xp + (size_t)b * TPADDED * DPAD;
    for (int idx = tid; idx < CROWS * (DPAD / 8); idx += 256) {
      int rr = idx / 40, c8 = idx % 40;
      int tp = t0 + rr;
      int4 v = make_int4(0, 0, 0, 0);
      if (tp < TPADDED) v = *(const int4*)&src[(size_t)tp * DPAD + c8 * 8];
      *(int4*)&xls[rr * CSTRIDE + c8 * 8] = v;
    }
  }
  __syncthreads();
  int ww = tid >> 6, lane = tid & 63;
  int wo = ww & 1, wt = ww >> 1;
  int l15 = lane & 15, quad = lane >> 4;
  int ob = oh * 160 + wo * 80;
  f4v acc[5][2];
#pragma unroll
  for (int mf = 0; mf < 5; ++mf) {
    float bv[4];
#pragma unroll
    for (int rr = 0; rr < 4; ++rr) {
      int o = ob + mf * 16 + quad * 4 + rr;
      bv[rr] = (o < DDIM) ? bias[o] : 0.0f;
    }
#pragma unroll
    for (int nf = 0; nf < 2; ++nf) {
      acc[mf][nf][0] = bv[0]; acc[mf][nf][1] = bv[1];
      acc[mf][nf][2] = bv[2]; acc[mf][nf][3] = bv[3];
    }
  }
  s8v Acur[5], Anext[5];
#pragma unroll
  for (int mf = 0; mf < 5; ++mf)
    Acur[mf] = *(const s8v*)&wT[(size_t)(ob + mf * 16 + l15) * DPAD + quad * 8];
#pragma unroll 10
  for (int iter = 0; iter < 100; ++iter) {
    int kc = iter / 10, it = iter % 10;
    if (iter < 99) {
      int kn = (iter + 1) / 10, itn = (iter + 1) % 10;
#pragma unroll
      for (int mf = 0; mf < 5; ++mf)
        Anext[mf] = *(const s8v*)&wT[((size_t)kn * DPAD + ob + mf * 16 + l15) * DPAD + itn * 32 + quad * 8];
    }
    s8v Bv[2];
#pragma unroll
    for (int nf = 0; nf < 2; ++nf) {
      int rrow = wt * 32 + nf * 16 + l15 + kc;
      Bv[nf] = *(const s8v*)&xls[rrow * CSTRIDE + it * 32 + quad * 8];
    }
#pragma unroll
    for (int mf = 0; mf < 5; ++mf)
#pragma unroll
      for (int nf = 0; nf < 2; ++nf)
        acc[mf][nf] = __builtin_amdgcn_mfma_f32_16x16x32_bf16(Acur[mf], Bv[nf], acc[mf][nf], 0, 0, 0);
#pragma unroll
    for (int mf = 0; mf < 5; ++mf) Acur[mf] = Anext[mf];
  }
#pragma unroll
  for (int mf = 0; mf < 5; ++mf) {
    int obase = ob + mf * 16 + quad * 4;
#pragma unroll
    for (int nf = 0; nf < 2; ++nf) {
      int t = t0 + wt * 32 + nf * 16 + l15;
      if (t < TALLOC) {
        bool live = t < TPRIME;
        unsigned short pk[4];
#pragma unroll
        for (int rr = 0; rr < 4; ++rr)
          pk[rr] = live ? f2bf(fmaxf(acc[mf][nf][rr], 0.0f)) : (unsigned short)0;
        *(uint2*)&h[((size_t)b * TALLOC + t) * DPAD + obase] = *(uint2*)pk;
      }
    }
  }
}

// ---- K5: scores (U . h) via MFMA + fused softmax-weighted mean.
// Waves split L (32 l each); all 20 U A-frags live in 80 VGPRs, loaded once.
// h streamed via global_load_lds DMA (no staging VGPRs / ds_writes):
//   linear LDS dest + involution-swizzled SOURCE chunks (c ^= r&7 within
//   128B groups) + same XOR on read side (rule #21) -> conflict-free reads
//   with pad-free 640B rows (LDS 40960B -> 3 blocks/CU).
// Depth-1 prefetch; raw s_barrier + vmcnt(0) drained a full tile after issue.
__global__ __launch_bounds__(256, 3) void attn_mfma_kernel(
    const unsigned short* __restrict__ h, const unsigned short* __restrict__ Ub,
    const float* __restrict__ fcb, float* __restrict__ out) {
  __shared__ unsigned short hls[2 * TSTG * DPAD];   // 2 x 10240 elems = 40960B
  int b = blockIdx.x & 7, lb = blockIdx.x >> 3;
  int tid = threadIdx.x;
  int w = tid >> 6, lane = tid & 63;
  int l15 = lane & 15, quad = lane >> 4;
  const unsigned short* hb = h + (size_t)b * TALLOC * DPAD;

  // A fragments (U) in registers for the whole kernel: wave covers 32 l-rows
  s8v A[2][10];
  {
    int lr0 = lb * 128 + w * 32 + l15;
#pragma unroll
    for (int mf = 0; mf < 2; ++mf) {
      int lr = lr0 + mf * 16;
      if (lr >= LPAD) lr = LPAD - 1;          // clamped rows masked at store
      const unsigned short* up = Ub + (size_t)lr * DPAD + quad * 8;
#pragma unroll
      for (int kc = 0; kc < 10; ++kc)
        A[mf][kc] = *(const s8v*)&up[kc * 32];
    }
  }

  // DMA staging map: wave w fills LDS elems [w*2560, w*2560+2560) in 5 x 1KB.
  // lane's LDS chunk g = w*320 + j*64 + lane -> row r = g/40, chunk c = g%40;
  // global source chunk = c ^ (r&7)  (involution, stays in 128B group)
  int srcoff[5];
#pragma unroll
  for (int j = 0; j < 5; ++j) {
    int g = w * 320 + j * 64 + lane;
    int r = g / 40, c = g % 40;
    srcoff[j] = r * DPAD + ((c ^ (r & 7)) * 8);
  }

  // prologue: DMA tile 0 -> buf0
#pragma unroll
  for (int j = 0; j < 5; ++j)
    __builtin_amdgcn_global_load_lds((gas_ptr)(const void*)(hb + srcoff[j]),
                                     (las_ptr)(void*)&hls[w * 2560 + j * 512],
                                     16, 0, 0);
  asm volatile("s_waitcnt vmcnt(0)" ::: "memory");
  __builtin_amdgcn_s_barrier();

  float se[2][4], sw[2][4];
#pragma unroll
  for (int mf = 0; mf < 2; ++mf)
#pragma unroll
    for (int r = 0; r < 4; ++r) { se[mf][r] = 0.0f; sw[mf][r] = 0.0f; }

  int xr8 = (l15 & 7) * 8;            // read-side XOR (elem units)
  int rowb0 = l15 * DPAD;             // nf=0 row base
  int rowb1 = (16 + l15) * DPAD;      // nf=1 row base
  int bufsel = 0;
  for (int t = 0; t < NTT; ++t) {
    // issue DMA for tile t+1 into the other buffer (latency hidden by compute)
    if (t + 1 < NTT) {
      const unsigned short* src = hb + (size_t)(t + 1) * TSTG * DPAD;
      int dstb = (bufsel ^ 1) * 10240 + w * 2560;
#pragma unroll
      for (int j = 0; j < 5; ++j)
        __builtin_amdgcn_global_load_lds((gas_ptr)(const void*)(src + srcoff[j]),
                                         (las_ptr)(void*)&hls[dstb + j * 512],
                                         16, 0, 0);
    }
    const unsigned short* bufc = &hls[bufsel * 10240];
    f4v acc[2][2];
#pragma unroll
    for (int mf = 0; mf < 2; ++mf)
#pragma unroll
      for (int nf = 0; nf < 2; ++nf) {
        acc[mf][nf][0] = 0.0f; acc[mf][nf][1] = 0.0f;
        acc[mf][nf][2] = 0.0f; acc[mf][nf][3] = 0.0f;
      }
#pragma unroll
    for (int kc = 0; kc < 10; ++kc) {
      int ko = (kc * 32 + quad * 8) ^ xr8;
      s8v Bv0 = *(const s8v*)&bufc[rowb0 + ko];
      s8v Bv1 = *(const s8v*)&bufc[rowb1 + ko];
      acc[0][0] = __builtin_amdgcn_mfma_f32_16x16x32_bf16(A[0][kc], Bv0, acc[0][0], 0, 0, 0);
      acc[0][1] = __builtin_amdgcn_mfma_f32_16x16x32_bf16(A[0][kc], Bv1, acc[0][1], 0, 0, 0);
      acc[1][0] = __builtin_amdgcn_mfma_f32_16x16x32_bf16(A[1][kc], Bv0, acc[1][0], 0, 0, 0);
      acc[1][1] = __builtin_amdgcn_mfma_f32_16x16x32_bf16(A[1][kc], Bv1, acc[1][1], 0, 0, 0);
    }
    // fused softmax-weighted accumulation (tail rows of h are zeros, t>=TPRIME masked)
    int tb0 = t * TSTG;
#pragma unroll
    for (int nf = 0; nf < 2; ++nf) {
      bool valid = (tb0 + nf * 16 + l15) < TPRIME;
#pragma unroll
      for (int mf = 0; mf < 2; ++mf)
#pragma unroll
        for (int r = 0; r < 4; ++r) {
          float s = acc[mf][nf][r];
          float e = valid ? __expf(s) : 0.0f;
          se[mf][r] += e;
          sw[mf][r] = fmaf(e, valid ? s : 0.0f, sw[mf][r]);
        }
    }
    // drain this iter's DMA (issued ~a full tile of compute ago), sync, swap
    asm volatile("s_waitcnt vmcnt(0)" ::: "memory");
    __builtin_amdgcn_s_barrier();
    bufsel ^= 1;
  }

  // reduce over the 16 t-columns (l15 lanes) — no cross-wave reduction needed
#pragma unroll
  for (int mf = 0; mf < 2; ++mf)
#pragma unroll
    for (int r = 0; r < 4; ++r) {
      float a = se[mf][r], c = sw[mf][r];
#pragma unroll
      for (int off = 1; off < 16; off <<= 1) {
        a += __shfl_xor(a, off, 64);
        c += __shfl_xor(c, off, 64);
      }
      if (l15 == 0) {
        int l = lb * 128 + w * 32 + mf * 16 + quad * 4 + r;
        if (l < LDIM) out[(size_t)b * LDIM + l] = c / a + fcb[l];
      }
    }
}

extern "C" void kernel_launch(void* const* d_in, const int* in_sizes, int n_in,
                              void* d_out, int out_size, void* d_ws, size_t ws_size,
                              hipStream_t stream) {
  const int*   ids     = (const int*)d_in[0];
  const float* embed_w = (const float*)d_in[1];
  const float* conv_w  = (const float*)d_in[2];
  const float* conv_b  = (const float*)d_in[3];
  const float* U       = (const float*)d_in[4];
  const float* fc_bias = (const float*)d_in[5];
  float* out = (float*)d_out;

  unsigned char* p = (unsigned char*)d_ws;
  unsigned short* xp = (unsigned short*)p;                 p += (size_t)BATCH * TPADDED * DPAD * 2;
  unsigned short* hb = (unsigned short*)p;                 p += (size_t)BATCH * TALLOC * DPAD * 2;
  unsigned short* wT = (unsigned short*)p;                 p += (size_t)KSZ * DPAD * DPAD * 2;
  unsigned short* Ub = (unsigned short*)p;

  hipLaunchKernelGGL(gather_kernel, dim3(BATCH * TPADDED / 4), dim3(256), 0, stream,
                     ids, embed_w, xp);
  hipLaunchKernelGGL(wt_kernel, dim3(KSZ * DPAD), dim3(256), 0, stream, conv_w, wT);
  hipLaunchKernelGGL(ut_kernel, dim3(LPAD), dim3(256), 0, stream, U, Ub);
  hipLaunchKernelGGL(conv_mfma_kernel, dim3(BATCH * 33 * 2), dim3(256), 0, stream,
                     xp, wT, conv_b, hb);
  hipLaunchKernelGGL(attn_mfma_kernel, dim3(BATCH * LBLK), dim3(256), 0, stream,
                     hb, Ub, fc_bias, out);
}

// Round 5
// 286.025 us; speedup vs baseline: 1.9162x; 1.3639x over previous
//
#include <hip/hip_runtime.h>

#define VOCAB   50000
#define LDIM    8921
#define DDIM    300
#define DPAD    320
#define KSZ     10
#define BATCH   8
#define TSEQ    2048
#define PADL    9
#define TPRIME  2057
#define TPADDED 2066
#define LPAD    8928

// ---- attn tiling
#define TSTG    32                 // t rows per LDS tile
#define NTT     65                 // ceil(TPRIME/TSTG)
#define TALLOC  (NTT * TSTG)       // 2080 h rows per batch (tail rows zeroed by conv)
#define LBLK    70                 // ceil(LDIM/128) l-blocks

typedef short s8v __attribute__((ext_vector_type(8)));   // 8 x bf16 bits
typedef float f4v __attribute__((ext_vector_type(4)));

typedef const __attribute__((address_space(1))) unsigned int* gas_ptr;
typedef __attribute__((address_space(3))) unsigned int* las_ptr;

__device__ inline unsigned short f2bf(float f) {
  union { float f; unsigned u; } v; v.f = f;
  unsigned r = v.u + 0x7FFF + ((v.u >> 16) & 1);
  return (unsigned short)(r >> 16);
}

// ---- K1: embedding gather -> xp_bf16[b][tau][DPAD], zero-padded rows/cols
__global__ __launch_bounds__(256) void gather_kernel(
    const int* __restrict__ ids, const float* __restrict__ embed_w,
    unsigned short* __restrict__ xp) {
  int wid = blockIdx.x * 4 + (threadIdx.x >> 6);
  int lane = threadIdx.x & 63;
  int b = wid / TPADDED, tau = wid % TPADDED;
  bool inr = (tau >= PADL) && (tau < PADL + TSEQ);
  int row = inr ? ids[b * TSEQ + (tau - PADL)] : 0;
  const float* src = embed_w + (size_t)row * DDIM;
  unsigned short* dst = xp + ((size_t)b * TPADDED + tau) * DPAD;
#pragma unroll
  for (int j = 0; j < 3; ++j) {
    int c2 = (j * 64 + lane) * 2;
    if (c2 < DPAD) {
      float v0 = (inr && c2 < DDIM) ? src[c2] : 0.0f;
      float v1 = (inr && c2 + 1 < DDIM) ? src[c2 + 1] : 0.0f;
      unsigned pk = (unsigned)f2bf(v0) | ((unsigned)f2bf(v1) << 16);
      *(unsigned*)&dst[c2] = pk;
    }
  }
}

// ---- K2: conv weight transform -> wT[k][o][i] bf16, o/i padded to 320 with 0
__global__ __launch_bounds__(256) void wt_kernel(
    const float* __restrict__ w, unsigned short* __restrict__ wT) {
  int k = blockIdx.x / DPAD, o = blockIdx.x % DPAD;
  for (int i = threadIdx.x; i < DPAD; i += 256) {
    float v = (o < DDIM && i < DDIM) ? w[((size_t)o * DDIM + i) * KSZ + k] : 0.0f;
    wT[((size_t)k * DPAD + o) * DPAD + i] = f2bf(v);
  }
}

// ---- K3: U transform -> Ub[l][d] bf16, l padded to 8928, d to 320 with 0
__global__ __launch_bounds__(256) void ut_kernel(
    const float* __restrict__ U, unsigned short* __restrict__ Ub) {
  int l = blockIdx.x;
  for (int d = threadIdx.x; d < DPAD; d += 256) {
    float v = (l < LDIM && d < DDIM) ? U[(size_t)l * DDIM + d] : 0.0f;
    Ub[(size_t)l * DPAD + d] = f2bf(v);
  }
}

// ---- K4: conv via MFMA — balanced grid + distance-2 wT prefetch.
// Evidence (r2/r4): makespan = (max blocks/CU) x block_time; block_time set by
// the 100-iter dependent chain (wT L3-latency exposed at prefetch distance 1),
// nearly independent of per-iter MFMA count; co-resident waves barely overlap.
// Fix: t-tile 80 (2080 = 26x80 exact) -> 208 blocks, <=1/CU, zero makespan
// quantization. Wave = o-quadrant x 5 t-frags (acc[5][5], 25 MFMA/iter).
// wT prefetch distance 2 via manual Aping/Apong (NO unroll pragma, NO tight
// launch_bounds — both proved harmful r3/r4). ~190 VGPR live set, cap 256+.
#define CTN 80
#define CROWS 89          // CTN + KSZ - 1
#define CSTRIDE 328       // 656B/row -> benign 2-way conflicts
__global__ __launch_bounds__(256) void conv_mfma_kernel(
    const unsigned short* __restrict__ xp, const unsigned short* __restrict__ wT,
    const float* __restrict__ bias, unsigned short* __restrict__ h) {
  __shared__ unsigned short xls[CROWS * CSTRIDE];   // 58384 B
  int b = blockIdx.x & 7, tb = blockIdx.x >> 3;     // grid 208 = 8 x 26
  int t0 = tb * CTN;
  int tid = threadIdx.x;
  {
    const unsigned short* src = xp + (size_t)b * TPADDED * DPAD;
    for (int idx = tid; idx < CROWS * 40; idx += 256) {
      int rr = idx / 40, c8 = idx % 40;
      int tp = t0 + rr;
      int4 v = make_int4(0, 0, 0, 0);
      if (tp < TPADDED) v = *(const int4*)&src[(size_t)tp * DPAD + c8 * 8];
      *(int4*)&xls[rr * CSTRIDE + c8 * 8] = v;
    }
  }
  __syncthreads();
  int w = tid >> 6, lane = tid & 63;
  int l15 = lane & 15, quad = lane >> 4;
  int ob = w * 80;                                  // o-quadrant per wave
  f4v acc[5][5];
#pragma unroll
  for (int mf = 0; mf < 5; ++mf) {
    float bv[4];
#pragma unroll
    for (int rr = 0; rr < 4; ++rr) {
      int o = ob + mf * 16 + quad * 4 + rr;
      bv[rr] = (o < DDIM) ? bias[o] : 0.0f;
    }
#pragma unroll
    for (int nf = 0; nf < 5; ++nf) {
      acc[mf][nf][0] = bv[0]; acc[mf][nf][1] = bv[1];
      acc[mf][nf][2] = bv[2]; acc[mf][nf][3] = bv[3];
    }
  }
  // A-frag (kc,it,mf) at wl[kc*DPAD*DPAD + mf*16*DPAD + it*32]
  const unsigned short* wl = wT + (size_t)(ob + l15) * DPAD + quad * 8;
  s8v Aping[5], Apong[5];
#pragma unroll
  for (int mf = 0; mf < 5; ++mf) Aping[mf] = *(const s8v*)&wl[mf * 16 * DPAD];        // (0,0)
#pragma unroll
  for (int mf = 0; mf < 5; ++mf) Apong[mf] = *(const s8v*)&wl[mf * 16 * DPAD + 32];   // (0,1)
  for (int ii = 0; ii < 100; ii += 2) {
    // ---- even sub-iter: frags (ii) in Aping
    {
      int kc = ii / 10, it = ii % 10;
      s8v Bv[5];
#pragma unroll
      for (int nf = 0; nf < 5; ++nf)
        Bv[nf] = *(const s8v*)&xls[(nf * 16 + l15 + kc) * CSTRIDE + it * 32 + quad * 8];
#pragma unroll
      for (int mf = 0; mf < 5; ++mf)
#pragma unroll
        for (int nf = 0; nf < 5; ++nf)
          acc[mf][nf] = __builtin_amdgcn_mfma_f32_16x16x32_bf16(Aping[mf], Bv[nf], acc[mf][nf], 0, 0, 0);
      int p = ii + 2;
      if (p < 100) {
        int kp = p / 10, itp = p % 10;
        const unsigned short* wp = wl + (size_t)kp * (DPAD * DPAD) + itp * 32;
#pragma unroll
        for (int mf = 0; mf < 5; ++mf) Aping[mf] = *(const s8v*)&wp[mf * 16 * DPAD];
      }
    }
    // ---- odd sub-iter: frags (ii+1) in Apong
    {
      int kc = (ii + 1) / 10, it = (ii + 1) % 10;
      s8v Bv[5];
#pragma unroll
      for (int nf = 0; nf < 5; ++nf)
        Bv[nf] = *(const s8v*)&xls[(nf * 16 + l15 + kc) * CSTRIDE + it * 32 + quad * 8];
#pragma unroll
      for (int mf = 0; mf < 5; ++mf)
#pragma unroll
        for (int nf = 0; nf < 5; ++nf)
          acc[mf][nf] = __builtin_amdgcn_mfma_f32_16x16x32_bf16(Apong[mf], Bv[nf], acc[mf][nf], 0, 0, 0);
      int p = ii + 3;
      if (p < 100) {
        int kp = p / 10, itp = p % 10;
        const unsigned short* wp = wl + (size_t)kp * (DPAD * DPAD) + itp * 32;
#pragma unroll
        for (int mf = 0; mf < 5; ++mf) Apong[mf] = *(const s8v*)&wp[mf * 16 * DPAD];
      }
    }
  }
#pragma unroll
  for (int mf = 0; mf < 5; ++mf) {
    int obase = ob + mf * 16 + quad * 4;
#pragma unroll
    for (int nf = 0; nf < 5; ++nf) {
      int t = t0 + nf * 16 + l15;            // always < TALLOC (26x80 = 2080 exact)
      bool live = t < TPRIME;
      unsigned short pk[4];
#pragma unroll
      for (int rr = 0; rr < 4; ++rr)
        pk[rr] = live ? f2bf(fmaxf(acc[mf][nf][rr], 0.0f)) : (unsigned short)0;
      *(uint2*)&h[((size_t)b * TALLOC + t) * DPAD + obase] = *(uint2*)pk;
    }
  }
}

// ---- K5: scores (U . h) via MFMA + fused softmax-weighted mean.
// Waves split L (32 l each); all 20 U A-frags live in 80 VGPRs, loaded once.
// h streamed via global_load_lds DMA; linear LDS dest + involution-swizzled
// SOURCE chunks + same XOR on read side -> conflict-free, 3 blocks/CU.
__global__ __launch_bounds__(256, 3) void attn_mfma_kernel(
    const unsigned short* __restrict__ h, const unsigned short* __restrict__ Ub,
    const float* __restrict__ fcb, float* __restrict__ out) {
  __shared__ unsigned short hls[2 * TSTG * DPAD];   // 2 x 10240 elems = 40960B
  int b = blockIdx.x & 7, lb = blockIdx.x >> 3;
  int tid = threadIdx.x;
  int w = tid >> 6, lane = tid & 63;
  int l15 = lane & 15, quad = lane >> 4;
  const unsigned short* hb = h + (size_t)b * TALLOC * DPAD;

  s8v A[2][10];
  {
    int lr0 = lb * 128 + w * 32 + l15;
#pragma unroll
    for (int mf = 0; mf < 2; ++mf) {
      int lr = lr0 + mf * 16;
      if (lr >= LPAD) lr = LPAD - 1;
      const unsigned short* up = Ub + (size_t)lr * DPAD + quad * 8;
#pragma unroll
      for (int kc = 0; kc < 10; ++kc)
        A[mf][kc] = *(const s8v*)&up[kc * 32];
    }
  }

  int srcoff[5];
#pragma unroll
  for (int j = 0; j < 5; ++j) {
    int g = w * 320 + j * 64 + lane;
    int r = g / 40, c = g % 40;
    srcoff[j] = r * DPAD + ((c ^ (r & 7)) * 8);
  }

#pragma unroll
  for (int j = 0; j < 5; ++j)
    __builtin_amdgcn_global_load_lds((gas_ptr)(const void*)(hb + srcoff[j]),
                                     (las_ptr)(void*)&hls[w * 2560 + j * 512],
                                     16, 0, 0);
  asm volatile("s_waitcnt vmcnt(0)" ::: "memory");
  __builtin_amdgcn_s_barrier();

  float se[2][4], sw[2][4];
#pragma unroll
  for (int mf = 0; mf < 2; ++mf)
#pragma unroll
    for (int r = 0; r < 4; ++r) { se[mf][r] = 0.0f; sw[mf][r] = 0.0f; }

  int xr8 = (l15 & 7) * 8;
  int rowb0 = l15 * DPAD;
  int rowb1 = (16 + l15) * DPAD;
  int bufsel = 0;
  for (int t = 0; t < NTT; ++t) {
    if (t + 1 < NTT) {
      const unsigned short* src = hb + (size_t)(t + 1) * TSTG * DPAD;
      int dstb = (bufsel ^ 1) * 10240 + w * 2560;
#pragma unroll
      for (int j = 0; j < 5; ++j)
        __builtin_amdgcn_global_load_lds((gas_ptr)(const void*)(src + srcoff[j]),
                                         (las_ptr)(void*)&hls[dstb + j * 512],
                                         16, 0, 0);
    }
    const unsigned short* bufc = &hls[bufsel * 10240];
    f4v acc[2][2];
#pragma unroll
    for (int mf = 0; mf < 2; ++mf)
#pragma unroll
      for (int nf = 0; nf < 2; ++nf) {
        acc[mf][nf][0] = 0.0f; acc[mf][nf][1] = 0.0f;
        acc[mf][nf][2] = 0.0f; acc[mf][nf][3] = 0.0f;
      }
#pragma unroll
    for (int kc = 0; kc < 10; ++kc) {
      int ko = (kc * 32 + quad * 8) ^ xr8;
      s8v Bv0 = *(const s8v*)&bufc[rowb0 + ko];
      s8v Bv1 = *(const s8v*)&bufc[rowb1 + ko];
      acc[0][0] = __builtin_amdgcn_mfma_f32_16x16x32_bf16(A[0][kc], Bv0, acc[0][0], 0, 0, 0);
      acc[0][1] = __builtin_amdgcn_mfma_f32_16x16x32_bf16(A[0][kc], Bv1, acc[0][1], 0, 0, 0);
      acc[1][0] = __builtin_amdgcn_mfma_f32_16x16x32_bf16(A[1][kc], Bv0, acc[1][0], 0, 0, 0);
      acc[1][1] = __builtin_amdgcn_mfma_f32_16x16x32_bf16(A[1][kc], Bv1, acc[1][1], 0, 0, 0);
    }
    int tb0 = t * TSTG;
#pragma unroll
    for (int nf = 0; nf < 2; ++nf) {
      bool valid = (tb0 + nf * 16 + l15) < TPRIME;
#pragma unroll
      for (int mf = 0; mf < 2; ++mf)
#pragma unroll
        for (int r = 0; r < 4; ++r) {
          float s = acc[mf][nf][r];
          float e = valid ? __expf(s) : 0.0f;
          se[mf][r] += e;
          sw[mf][r] = fmaf(e, valid ? s : 0.0f, sw[mf][r]);
        }
    }
    asm volatile("s_waitcnt vmcnt(0)" ::: "memory");
    __builtin_amdgcn_s_barrier();
    bufsel ^= 1;
  }

#pragma unroll
  for (int mf = 0; mf < 2; ++mf)
#pragma unroll
    for (int r = 0; r < 4; ++r) {
      float a = se[mf][r], c = sw[mf][r];
#pragma unroll
      for (int off = 1; off < 16; off <<= 1) {
        a += __shfl_xor(a, off, 64);
        c += __shfl_xor(c, off, 64);
      }
      if (l15 == 0) {
        int l = lb * 128 + w * 32 + mf * 16 + quad * 4 + r;
        if (l < LDIM) out[(size_t)b * LDIM + l] = c / a + fcb[l];
      }
    }
}

extern "C" void kernel_launch(void* const* d_in, const int* in_sizes, int n_in,
                              void* d_out, int out_size, void* d_ws, size_t ws_size,
                              hipStream_t stream) {
  const int*   ids     = (const int*)d_in[0];
  const float* embed_w = (const float*)d_in[1];
  const float* conv_w  = (const float*)d_in[2];
  const float* conv_b  = (const float*)d_in[3];
  const float* U       = (const float*)d_in[4];
  const float* fc_bias = (const float*)d_in[5];
  float* out = (float*)d_out;

  unsigned char* p = (unsigned char*)d_ws;
  unsigned short* xp = (unsigned short*)p;                 p += (size_t)BATCH * TPADDED * DPAD * 2;
  unsigned short* hb = (unsigned short*)p;                 p += (size_t)BATCH * TALLOC * DPAD * 2;
  unsigned short* wT = (unsigned short*)p;                 p += (size_t)KSZ * DPAD * DPAD * 2;
  unsigned short* Ub = (unsigned short*)p;

  hipLaunchKernelGGL(gather_kernel, dim3(BATCH * TPADDED / 4), dim3(256), 0, stream,
                     ids, embed_w, xp);
  hipLaunchKernelGGL(wt_kernel, dim3(KSZ * DPAD), dim3(256), 0, stream, conv_w, wT);
  hipLaunchKernelGGL(ut_kernel, dim3(LPAD), dim3(256), 0, stream, U, Ub);
  hipLaunchKernelGGL(conv_mfma_kernel, dim3(BATCH * 26), dim3(256), 0, stream,
                     xp, wT, conv_b, hb);
  hipLaunchKernelGGL(attn_mfma_kernel, dim3(BATCH * LBLK), dim3(256), 0, stream,
                     hb, Ub, fc_bias, out);
}